// Round 13
// baseline (89.785 us; speedup 1.0000x reference)
//
#include <hip/hip_runtime.h>
#include <hip/hip_bf16.h>

#define N 4096
#define D 768
#define NC 6    // D/128 K-chunks per gemm pass

typedef float f32x4 __attribute__((ext_vector_type(4)));
typedef int v8i __attribute__((ext_vector_type(8)));

typedef __attribute__((address_space(3))) unsigned int as3_uint;
typedef const __attribute__((address_space(1))) unsigned int as1_uint;

__device__ __forceinline__ void gload16(const void* g, void* l) {
    __builtin_amdgcn_global_load_lds((as1_uint*)g, (as3_uint*)l, 16, 0, 0);
}

// Tiled fp8 global layout for mfma_scale_f32_16x16x128_f8f6f4 (R7-verified):
// frag-tile = 16 rows x 128 k = 2048B, tile index (R>>4)*6 + (k>>7).
// Within a tile: lane l = (R&15) + 16*((k&127)>>5) holds 32 contiguous k,
// stored as two lane-linear 1024B halves (byte = half*1024 + l*16 + (k&15)).
// -> operand = two 16B loads at p and p+1024 (global or LDS, conflict-free).

// ---------------- normalize: f32 [N][D] -> fp8 tiled, row L2-normalized ------
__global__ __launch_bounds__(256) void norm4(const float* __restrict__ x0,
                                             const float* __restrict__ x1,
                                             const float* __restrict__ x2,
                                             const float* __restrict__ x3,
                                             unsigned char* __restrict__ o) {
    int a = blockIdx.y;
    const float* x = (a == 0) ? x0 : (a == 1) ? x1 : (a == 2) ? x2 : x3;
    unsigned char* out = o + (size_t)a * N * D;
    int i0 = blockIdx.x * 32;                 // 32-row group
    __shared__ __align__(16) unsigned char tile[24576];
    int t = threadIdx.x, lane = t & 63, w = t >> 6;

    for (int rr = 0; rr < 8; ++rr) {
        int R = i0 + w * 8 + rr;
        const f32x4* xr = (const f32x4*)(x + (size_t)R * D);
        f32x4 v0 = xr[lane * 2], v1 = xr[lane * 2 + 1];
        f32x4 v2 = {}, v3 = {};
        if (lane < 32) { v2 = xr[128 + lane * 2]; v3 = xr[128 + lane * 2 + 1]; }
        float ss = v0[0]*v0[0] + v0[1]*v0[1] + v0[2]*v0[2] + v0[3]*v0[3]
                 + v1[0]*v1[0] + v1[1]*v1[1] + v1[2]*v1[2] + v1[3]*v1[3]
                 + v2[0]*v2[0] + v2[1]*v2[1] + v2[2]*v2[2] + v2[3]*v2[3]
                 + v3[0]*v3[0] + v3[1]*v3[1] + v3[2]*v3[2] + v3[3]*v3[3];
        #pragma unroll
        for (int m = 1; m < 64; m <<= 1) ss += __shfl_xor(ss, m);
        float s = 1.0f / fmaxf(sqrtf(ss), 1e-8f);

        int lrg = (R >> 4) & 1;
        {
            unsigned int wlo = __builtin_amdgcn_cvt_pk_fp8_f32(v0[0]*s, v0[1]*s, 0, false) & 0xffff;
            unsigned int whi = __builtin_amdgcn_cvt_pk_fp8_f32(v0[2]*s, v0[3]*s, 0, false) & 0xffff;
            unsigned int w0 = wlo | (whi << 16);
            wlo = __builtin_amdgcn_cvt_pk_fp8_f32(v1[0]*s, v1[1]*s, 0, false) & 0xffff;
            whi = __builtin_amdgcn_cvt_pk_fp8_f32(v1[2]*s, v1[3]*s, 0, false) & 0xffff;
            unsigned int w1 = wlo | (whi << 16);
            int g = lane;
            int off = (lrg * 6 + (g >> 4)) * 2048 + ((g >> 1) & 1) * 1024
                    + ((R & 15) + 16 * ((g & 15) >> 2)) * 16 + (g & 1) * 8;
            *(uint2*)(tile + off) = make_uint2(w0, w1);
        }
        if (lane < 32) {
            unsigned int wlo = __builtin_amdgcn_cvt_pk_fp8_f32(v2[0]*s, v2[1]*s, 0, false) & 0xffff;
            unsigned int whi = __builtin_amdgcn_cvt_pk_fp8_f32(v2[2]*s, v2[3]*s, 0, false) & 0xffff;
            unsigned int w0 = wlo | (whi << 16);
            wlo = __builtin_amdgcn_cvt_pk_fp8_f32(v3[0]*s, v3[1]*s, 0, false) & 0xffff;
            whi = __builtin_amdgcn_cvt_pk_fp8_f32(v3[2]*s, v3[3]*s, 0, false) & 0xffff;
            unsigned int w1 = wlo | (whi << 16);
            int g = 64 + lane;
            int off = (lrg * 6 + (g >> 4)) * 2048 + ((g >> 1) & 1) * 1024
                    + ((R & 15) + 16 * ((g & 15) >> 2)) * 16 + (g & 1) * 8;
            *(uint2*)(tile + off) = make_uint2(w0, w1);
        }
    }
    __syncthreads();
    unsigned char* dst = out + (size_t)(i0 >> 5) * 24576;
    #pragma unroll
    for (int i = 0; i < 6; ++i)
        ((int4*)dst)[t + i * 256] = ((const int4*)tile)[t + i * 256];
}

// ---------------- one gemm pass: acc += A_blk(128) x B_blk(128)^T ------------
// R7/R12-verified structure: BK=128 chunks, LDS buffer 32KB (A 8 frag-tiles
// @0, B @16384), dbuf 64KB, 2 blocks/CU. Per chunk: ISSUE(c+1) 8 gloads ->
// vmcnt(8) [c fully staged; c+1 in flight] -> barrier -> 16 ds_read_b128 ->
// 16 MFMA(K=128, scales=1) -> barrier.
__device__ __forceinline__ void gemm_pass(const unsigned char* __restrict__ A,
                                          const unsigned char* __restrict__ B,
                                          char* smem, int ib, int jb, int t,
                                          f32x4 (&acc)[4][4]) {
    const int lane = t & 63, w = t >> 6;
    const int wm = w >> 1, wn = w & 1;

    // staging: wave w covers A frag-tiles {2w, 2w+1}, B frag-tiles {2w, 2w+1}
    const unsigned char* gA = A + (size_t)((ib * 8 + 2 * w) * 6) * 2048 + lane * 16;
    const unsigned char* gB = B + (size_t)((jb * 8 + 2 * w) * 6) * 2048 + lane * 16;
    const int sd = w * 4096 + lane * 16;

    #define ISSUE(c)  do {                                                     \
        char* buf = smem + ((c) & 1) * 32768;                                  \
        const unsigned char* sa = gA + (c) * 2048;                             \
        const unsigned char* sb = gB + (c) * 2048;                             \
        gload16(sa,         buf + sd);                                         \
        gload16(sa + 1024,  buf + sd + 1024);                                  \
        gload16(sa + 12288, buf + sd + 2048);                                  \
        gload16(sa + 13312, buf + sd + 3072);                                  \
        gload16(sb,         buf + 16384 + sd);                                 \
        gload16(sb + 1024,  buf + 16384 + sd + 1024);                          \
        gload16(sb + 12288, buf + 16384 + sd + 2048);                          \
        gload16(sb + 13312, buf + 16384 + sd + 3072);                          \
    } while (0)

    ISSUE(0);

    #pragma unroll 1
    for (int c = 0; c < NC; ++c) {
        if (c < NC - 1) {
            ISSUE(c + 1);
            asm volatile("s_waitcnt vmcnt(8)" ::: "memory");  // c staged, c+1 in flight
        } else {
            asm volatile("s_waitcnt vmcnt(0)" ::: "memory");  // tail: drain all
        }
        __builtin_amdgcn_s_barrier();
        asm volatile("" ::: "memory");

        const char* cb = smem + (c & 1) * 32768;
        union { int4 q[2]; v8i v; } a[4], b[4];
        #pragma unroll
        for (int m = 0; m < 4; ++m) {
            const char* p = cb + (wm * 4 + m) * 2048 + lane * 16;
            a[m].q[0] = *(const int4*)p;
            a[m].q[1] = *(const int4*)(p + 1024);
        }
        #pragma unroll
        for (int n = 0; n < 4; ++n) {
            const char* p = cb + 16384 + (wn * 4 + n) * 2048 + lane * 16;
            b[n].q[0] = *(const int4*)p;
            b[n].q[1] = *(const int4*)(p + 1024);
        }
        __builtin_amdgcn_s_setprio(1);
        #pragma unroll
        for (int m = 0; m < 4; ++m)
            #pragma unroll
            for (int n = 0; n < 4; ++n)
                acc[m][n] = __builtin_amdgcn_mfma_scale_f32_16x16x128_f8f6f4(
                    a[m].v, b[n].v, acc[m][n], 0, 0, 0, 127, 0, 127);
        __builtin_amdgcn_s_setprio(0);
        __builtin_amdgcn_s_barrier();   // all reads of buffer c done
    }
    #undef ISSUE
}

__global__ __launch_bounds__(256, 2) void fused_gemm(
        const unsigned char* __restrict__ Xs, const unsigned char* __restrict__ Ys,
        const unsigned char* __restrict__ Xt, const unsigned char* __restrict__ Yt,
        float* __restrict__ partial) {
    __shared__ __align__(16) char smem[65536];
    const int t = threadIdx.x;
    // 2D XCD partition (R12-verified: FETCH 28->18.5 MB): xcd = bid&7.
    const int bid = blockIdx.x;
    const int xcd = bid & 7, loc = bid >> 3;          // loc 0..127
    const int ib = (xcd >> 1) * 8 + (loc & 7);
    const int jb = (xcd & 1) * 16 + (loc >> 3);
    const int i0 = ib * 128;
    const int lane = t & 63, wid = t >> 6;
    const int wm = wid >> 1, wn = wid & 1;

    f32x4 acc_s[4][4] = {};
    f32x4 acc_t[4][4] = {};

    gemm_pass(Xs, Ys, smem, ib, jb, t, acc_s);
    gemm_pass(Xt, Yt, smem, ib, jb, t, acc_t);

    // ---- epilogue (R6-validated halving tree): per-row partials, 128 cols ----
    __syncthreads();
    float* part = (float*)smem;      // [2 wn][128 rows][4 stats]
    const int g = lane >> 4, cl = lane & 15;
    // halving-tree leaves lane cl holding sum of v[rev4(cl)]
    const int idx = ((cl & 1) << 3) | ((cl & 2) << 1) | ((cl & 4) >> 1) | ((cl & 8) >> 3);
    const int rsel = idx >> 2, ssel = idx & 3;
    const int rowbase = wm * 64 + g * 4 + rsel;

    #pragma unroll
    for (int m = 0; m < 4; ++m) {
        float v[16];
        #pragma unroll
        for (int i = 0; i < 16; ++i) v[i] = 0.f;
        #pragma unroll
        for (int n = 0; n < 4; ++n)
            #pragma unroll
            for (int rr = 0; rr < 4; ++rr) {
                float ls = 10.0f * acc_s[m][n][rr];
                float lt = 10.0f * acc_t[m][n][rr];
                float es = __expf(ls - 10.0f);
                float et = __expf(lt - 10.0f);
                v[rr * 4 + 0] += es;
                v[rr * 4 + 1] += et;
                v[rr * 4 + 2] += es * (ls - lt);
                v[rr * 4 + 3] += et * (lt - ls);
            }
        // halving tree across the 16-lane group: 16 values -> 1 per lane
        #pragma unroll
        for (int stage = 0; stage < 4; ++stage) {
            const int msk = 1 << stage, half = 8 >> stage;
            const bool hi = (lane & msk) != 0;
            #pragma unroll
            for (int i = 0; i < half; ++i) {
                float send = hi ? v[i] : v[i + half];
                float recv = __shfl_xor(send, msk);
                v[i] = (hi ? v[i + half] : v[i]) + recv;
            }
        }
        part[(wn * 128 + rowbase + m * 16) * 4 + ssel] = v[0];
    }
    __syncthreads();
    #pragma unroll
    for (int q = 0; q < 2; ++q) {
        int idx2 = t + q * 256;      // 512 slots = 128 rows x 4 stats
        int row = idx2 >> 2, s = idx2 & 3;
        float v = part[(0 * 128 + row) * 4 + s] + part[(1 * 128 + row) * 4 + s];
        partial[((size_t)jb * N + (i0 + row)) * 4 + s] = v;
    }
}

// ---------------- per-row finalize + block partial sums ----------------------
__global__ __launch_bounds__(256) void reduce_rows(const float* __restrict__ partial,
                                                   float* __restrict__ blocksum) {
    int row = blockIdx.x * 256 + threadIdx.x;
    float zs = 0.f, zt = 0.f, ws = 0.f, wt = 0.f;
    for (int jb = 0; jb < 32; ++jb) {
        const float* p = partial + ((size_t)jb * N + row) * 4;
        zs += p[0]; zt += p[1]; ws += p[2]; wt += p[3];
    }
    float ls_row = wt / zt - logf(zt) + logf(zs);
    float lt_row = ws / zs - logf(zs) + logf(zt);
    #pragma unroll
    for (int m = 1; m < 64; m <<= 1) {
        ls_row += __shfl_xor(ls_row, m);
        lt_row += __shfl_xor(lt_row, m);
    }
    __shared__ float rs[4], rt[4];
    int lane = threadIdx.x & 63, wid = threadIdx.x >> 6;
    if (lane == 0) { rs[wid] = ls_row; rt[wid] = lt_row; }
    __syncthreads();
    if (threadIdx.x == 0) {
        blocksum[blockIdx.x * 2]     = rs[0] + rs[1] + rs[2] + rs[3];
        blocksum[blockIdx.x * 2 + 1] = rt[0] + rt[1] + rt[2] + rt[3];
    }
}

__global__ void final_reduce(const float* __restrict__ blocksum, float* __restrict__ out) {
    float a = 0.f, b = 0.f;
    if (threadIdx.x < 16) { a = blocksum[threadIdx.x * 2]; b = blocksum[threadIdx.x * 2 + 1]; }
    #pragma unroll
    for (int m = 1; m < 16; m <<= 1) { a += __shfl_xor(a, m); b += __shfl_xor(b, m); }
    if (threadIdx.x == 0) {
        const float inv = 1.0f / 16777216.0f;   // 1/N^2
        out[0] = a * inv;
        out[1] = b * inv;
    }
}

extern "C" void kernel_launch(void* const* d_in, const int* in_sizes, int n_in,
                              void* d_out, int out_size, void* d_ws, size_t ws_size,
                              hipStream_t stream) {
    const float* zxs = (const float*)d_in[0];
    const float* zys = (const float*)d_in[1];
    const float* zxt = (const float*)d_in[2];
    const float* zyt = (const float*)d_in[3];

    char* ws = (char*)d_ws;
    const size_t A = (size_t)N * D;                   // bytes per fp8 array
    unsigned char* nb = (unsigned char*)ws;           // 4 normalized fp8 arrays (tiled)
    float* partial  = (float*)(ws + 4 * A);           // [32][N][4] f32 = 2 MB
    float* blocksum = (float*)(ws + 4 * A + (size_t)32 * N * 4 * sizeof(float));

    norm4<<<dim3(N / 32, 4), 256, 0, stream>>>(zxs, zys, zxt, zyt, nb);

    const unsigned char* Xs = nb;
    const unsigned char* Ys = nb + A;
    const unsigned char* Xt = nb + 2 * A;
    const unsigned char* Yt = nb + 3 * A;
    fused_gemm<<<dim3(1024), 256, 0, stream>>>(Xs, Ys, Xt, Yt, partial);

    reduce_rows<<<16, 256, 0, stream>>>(partial, blocksum);
    final_reduce<<<1, 64, 0, stream>>>(blocksum, (float*)d_out);
}

// Round 14
// 53.549 us; speedup vs baseline: 1.6767x; 1.6767x over previous
//
#include <hip/hip_runtime.h>
#include <hip/hip_bf16.h>

#define N 4096
#define D 768
#define NC 6    // D/128 K-chunks per gemm pass

typedef float f32x4 __attribute__((ext_vector_type(4)));
typedef int v8i __attribute__((ext_vector_type(8)));

typedef __attribute__((address_space(3))) unsigned int as3_uint;
typedef const __attribute__((address_space(1))) unsigned int as1_uint;

__device__ __forceinline__ void gload16(const void* g, void* l) {
    __builtin_amdgcn_global_load_lds((as1_uint*)g, (as3_uint*)l, 16, 0, 0);
}

// Tiled fp8 global layout for mfma_scale_f32_16x16x128_f8f6f4 (R7-verified):
// frag-tile = 16 rows x 128 k = 2048B, tile index (R>>4)*6 + (k>>7).
// Within a tile: lane l = (R&15) + 16*((k&127)>>5) holds 32 contiguous k,
// stored as two lane-linear 1024B halves (byte = half*1024 + l*16 + (k&15)).
// -> operand = two 16B loads at p and p+1024 (global or LDS, conflict-free).

// ---------------- normalize: f32 [N][D] -> fp8 tiled, row L2-normalized ------
__global__ __launch_bounds__(256) void norm4(const float* __restrict__ x0,
                                             const float* __restrict__ x1,
                                             const float* __restrict__ x2,
                                             const float* __restrict__ x3,
                                             unsigned char* __restrict__ o) {
    int a = blockIdx.y;
    const float* x = (a == 0) ? x0 : (a == 1) ? x1 : (a == 2) ? x2 : x3;
    unsigned char* out = o + (size_t)a * N * D;
    int i0 = blockIdx.x * 32;                 // 32-row group
    __shared__ __align__(16) unsigned char tile[24576];
    int t = threadIdx.x, lane = t & 63, w = t >> 6;

    for (int rr = 0; rr < 8; ++rr) {
        int R = i0 + w * 8 + rr;
        const f32x4* xr = (const f32x4*)(x + (size_t)R * D);
        f32x4 v0 = xr[lane * 2], v1 = xr[lane * 2 + 1];
        f32x4 v2 = {}, v3 = {};
        if (lane < 32) { v2 = xr[128 + lane * 2]; v3 = xr[128 + lane * 2 + 1]; }
        float ss = v0[0]*v0[0] + v0[1]*v0[1] + v0[2]*v0[2] + v0[3]*v0[3]
                 + v1[0]*v1[0] + v1[1]*v1[1] + v1[2]*v1[2] + v1[3]*v1[3]
                 + v2[0]*v2[0] + v2[1]*v2[1] + v2[2]*v2[2] + v2[3]*v2[3]
                 + v3[0]*v3[0] + v3[1]*v3[1] + v3[2]*v3[2] + v3[3]*v3[3];
        #pragma unroll
        for (int m = 1; m < 64; m <<= 1) ss += __shfl_xor(ss, m);
        float s = 1.0f / fmaxf(sqrtf(ss), 1e-8f);

        int lrg = (R >> 4) & 1;
        {
            unsigned int wlo = __builtin_amdgcn_cvt_pk_fp8_f32(v0[0]*s, v0[1]*s, 0, false) & 0xffff;
            unsigned int whi = __builtin_amdgcn_cvt_pk_fp8_f32(v0[2]*s, v0[3]*s, 0, false) & 0xffff;
            unsigned int w0 = wlo | (whi << 16);
            wlo = __builtin_amdgcn_cvt_pk_fp8_f32(v1[0]*s, v1[1]*s, 0, false) & 0xffff;
            whi = __builtin_amdgcn_cvt_pk_fp8_f32(v1[2]*s, v1[3]*s, 0, false) & 0xffff;
            unsigned int w1 = wlo | (whi << 16);
            int g = lane;
            int off = (lrg * 6 + (g >> 4)) * 2048 + ((g >> 1) & 1) * 1024
                    + ((R & 15) + 16 * ((g & 15) >> 2)) * 16 + (g & 1) * 8;
            *(uint2*)(tile + off) = make_uint2(w0, w1);
        }
        if (lane < 32) {
            unsigned int wlo = __builtin_amdgcn_cvt_pk_fp8_f32(v2[0]*s, v2[1]*s, 0, false) & 0xffff;
            unsigned int whi = __builtin_amdgcn_cvt_pk_fp8_f32(v2[2]*s, v2[3]*s, 0, false) & 0xffff;
            unsigned int w0 = wlo | (whi << 16);
            wlo = __builtin_amdgcn_cvt_pk_fp8_f32(v3[0]*s, v3[1]*s, 0, false) & 0xffff;
            whi = __builtin_amdgcn_cvt_pk_fp8_f32(v3[2]*s, v3[3]*s, 0, false) & 0xffff;
            unsigned int w1 = wlo | (whi << 16);
            int g = 64 + lane;
            int off = (lrg * 6 + (g >> 4)) * 2048 + ((g >> 1) & 1) * 1024
                    + ((R & 15) + 16 * ((g & 15) >> 2)) * 16 + (g & 1) * 8;
            *(uint2*)(tile + off) = make_uint2(w0, w1);
        }
    }
    __syncthreads();
    unsigned char* dst = out + (size_t)(i0 >> 5) * 24576;
    #pragma unroll
    for (int i = 0; i < 6; ++i)
        ((int4*)dst)[t + i * 256] = ((const int4*)tile)[t + i * 256];
}

// ---------------- one gemm pass: acc += A_blk(128) x B_blk(128)^T ------------
// R7/R12-verified structure: BK=128 chunks, LDS buffer 32KB (A 8 frag-tiles
// @0, B @16384), dbuf 64KB, 2 blocks/CU. Per chunk: ISSUE(c+1) 8 gloads ->
// vmcnt(8) [c fully staged; c+1 in flight] -> barrier -> 16 ds_read_b128 ->
// 16 MFMA(K=128, scales=1) -> barrier.
__device__ __forceinline__ void gemm_pass(const unsigned char* __restrict__ A,
                                          const unsigned char* __restrict__ B,
                                          char* smem, int ib, int jb, int t,
                                          f32x4 (&acc)[4][4]) {
    const int lane = t & 63, w = t >> 6;
    const int wm = w >> 1, wn = w & 1;

    // staging: wave w covers A frag-tiles {2w, 2w+1}, B frag-tiles {2w, 2w+1}
    const unsigned char* gA = A + (size_t)((ib * 8 + 2 * w) * 6) * 2048 + lane * 16;
    const unsigned char* gB = B + (size_t)((jb * 8 + 2 * w) * 6) * 2048 + lane * 16;
    const int sd = w * 4096 + lane * 16;

    #define ISSUE(c)  do {                                                     \
        char* buf = smem + ((c) & 1) * 32768;                                  \
        const unsigned char* sa = gA + (c) * 2048;                             \
        const unsigned char* sb = gB + (c) * 2048;                             \
        gload16(sa,         buf + sd);                                         \
        gload16(sa + 1024,  buf + sd + 1024);                                  \
        gload16(sa + 12288, buf + sd + 2048);                                  \
        gload16(sa + 13312, buf + sd + 3072);                                  \
        gload16(sb,         buf + 16384 + sd);                                 \
        gload16(sb + 1024,  buf + 16384 + sd + 1024);                          \
        gload16(sb + 12288, buf + 16384 + sd + 2048);                          \
        gload16(sb + 13312, buf + 16384 + sd + 3072);                          \
    } while (0)

    ISSUE(0);

    #pragma unroll 1
    for (int c = 0; c < NC; ++c) {
        if (c < NC - 1) {
            ISSUE(c + 1);
            asm volatile("s_waitcnt vmcnt(8)" ::: "memory");  // c staged, c+1 in flight
        } else {
            asm volatile("s_waitcnt vmcnt(0)" ::: "memory");  // tail: drain all
        }
        __builtin_amdgcn_s_barrier();
        asm volatile("" ::: "memory");

        const char* cb = smem + (c & 1) * 32768;
        union { int4 q[2]; v8i v; } a[4], b[4];
        #pragma unroll
        for (int m = 0; m < 4; ++m) {
            const char* p = cb + (wm * 4 + m) * 2048 + lane * 16;
            a[m].q[0] = *(const int4*)p;
            a[m].q[1] = *(const int4*)(p + 1024);
        }
        #pragma unroll
        for (int n = 0; n < 4; ++n) {
            const char* p = cb + 16384 + (wn * 4 + n) * 2048 + lane * 16;
            b[n].q[0] = *(const int4*)p;
            b[n].q[1] = *(const int4*)(p + 1024);
        }
        __builtin_amdgcn_s_setprio(1);
        #pragma unroll
        for (int m = 0; m < 4; ++m)
            #pragma unroll
            for (int n = 0; n < 4; ++n)
                acc[m][n] = __builtin_amdgcn_mfma_scale_f32_16x16x128_f8f6f4(
                    a[m].v, b[n].v, acc[m][n], 0, 0, 0, 127, 0, 127);
        __builtin_amdgcn_s_setprio(0);
        __builtin_amdgcn_s_barrier();   // all reads of buffer c done
    }
    #undef ISSUE
}

__global__ __launch_bounds__(256, 2) void fused_gemm(
        const unsigned char* __restrict__ Xs, const unsigned char* __restrict__ Ys,
        const unsigned char* __restrict__ Xt, const unsigned char* __restrict__ Yt,
        float* __restrict__ partial) {
    __shared__ __align__(16) char smem[65536];
    const int t = threadIdx.x;
    // 2D XCD partition (R12-verified: FETCH 28->18.5 MB): xcd = bid&7.
    const int bid = blockIdx.x;
    const int xcd = bid & 7, loc = bid >> 3;          // loc 0..127
    const int ib = (xcd >> 1) * 8 + (loc & 7);
    const int jb = (xcd & 1) * 16 + (loc >> 3);
    const int i0 = ib * 128;
    const int lane = t & 63, wid = t >> 6;
    const int wm = wid >> 1, wn = wid & 1;

    f32x4 acc_s[4][4] = {};
    f32x4 acc_t[4][4] = {};

    gemm_pass(Xs, Ys, smem, ib, jb, t, acc_s);
    gemm_pass(Xt, Yt, smem, ib, jb, t, acc_t);

    // ---- epilogue v2: scatter-transpose via LDS, no shuffles ----------------
    // p2 layout: [32 slots][128 cells][4 f32] = 64KB, slot = wn*16+cl,
    // cell = row ^ (cl&7)  (XOR spreads the slot-major same-bank pathology;
    // each b128 write/read lands 8 lanes per bank-group -> even, no serial).
    __syncthreads();
    float* p2 = (float*)smem;
    const int g = lane >> 4, cl = lane & 15;
    const int slot = wn * 16 + cl;

    #pragma unroll
    for (int m = 0; m < 4; ++m)
        #pragma unroll
        for (int r = 0; r < 4; ++r) {
            float e0 = 0.f, e1 = 0.f, e2 = 0.f, e3 = 0.f;
            #pragma unroll
            for (int n = 0; n < 4; ++n) {
                float ls = 10.0f * acc_s[m][n][r];
                float lt = 10.0f * acc_t[m][n][r];
                float es = __expf(ls - 10.0f);
                float et = __expf(lt - 10.0f);
                e0 += es;
                e1 += et;
                e2 += es * (ls - lt);
                e3 += et * (lt - ls);
            }
            int row = wm * 64 + m * 16 + g * 4 + r;   // 0..127
            int cell = row ^ (cl & 7);
            f32x4 vv = {e0, e1, e2, e3};
            *(f32x4*)(p2 + slot * 512 + cell * 4) = vv;
        }
    __syncthreads();

    // reduce: thread t -> row = t>>1, half = t&1; vec4-sum its 16 slots
    {
        const int row = t >> 1, half = t & 1;
        f32x4 sum = {0.f, 0.f, 0.f, 0.f};
        #pragma unroll
        for (int j = 0; j < 16; ++j) {
            int sl = half * 16 + j;
            int cell = row ^ (sl & 7);
            sum += *(const f32x4*)(p2 + sl * 512 + cell * 4);
        }
        __syncthreads();                  // all reads of p2 done
        *(f32x4*)(p2 + t * 4) = sum;      // p3[256][4] = 4KB
    }
    __syncthreads();
    #pragma unroll
    for (int q = 0; q < 2; ++q) {
        int idx2 = t + q * 256;           // 512 slots = 128 rows x 4 stats
        int row = idx2 >> 2, s = idx2 & 3;
        float v = p2[(row * 2) * 4 + s] + p2[(row * 2 + 1) * 4 + s];
        partial[((size_t)jb * N + (i0 + row)) * 4 + s] = v;
    }
}

// ---------------- per-row finalize + block partial sums ----------------------
__global__ __launch_bounds__(256) void reduce_rows(const float* __restrict__ partial,
                                                   float* __restrict__ blocksum) {
    int row = blockIdx.x * 256 + threadIdx.x;
    float zs = 0.f, zt = 0.f, ws = 0.f, wt = 0.f;
    for (int jb = 0; jb < 32; ++jb) {
        const float* p = partial + ((size_t)jb * N + row) * 4;
        zs += p[0]; zt += p[1]; ws += p[2]; wt += p[3];
    }
    float ls_row = wt / zt - logf(zt) + logf(zs);
    float lt_row = ws / zs - logf(zs) + logf(zt);
    #pragma unroll
    for (int m = 1; m < 64; m <<= 1) {
        ls_row += __shfl_xor(ls_row, m);
        lt_row += __shfl_xor(lt_row, m);
    }
    __shared__ float rs[4], rt[4];
    int lane = threadIdx.x & 63, wid = threadIdx.x >> 6;
    if (lane == 0) { rs[wid] = ls_row; rt[wid] = lt_row; }
    __syncthreads();
    if (threadIdx.x == 0) {
        blocksum[blockIdx.x * 2]     = rs[0] + rs[1] + rs[2] + rs[3];
        blocksum[blockIdx.x * 2 + 1] = rt[0] + rt[1] + rt[2] + rt[3];
    }
}

__global__ void final_reduce(const float* __restrict__ blocksum, float* __restrict__ out) {
    float a = 0.f, b = 0.f;
    if (threadIdx.x < 16) { a = blocksum[threadIdx.x * 2]; b = blocksum[threadIdx.x * 2 + 1]; }
    #pragma unroll
    for (int m = 1; m < 16; m <<= 1) { a += __shfl_xor(a, m); b += __shfl_xor(b, m); }
    if (threadIdx.x == 0) {
        const float inv = 1.0f / 16777216.0f;   // 1/N^2
        out[0] = a * inv;
        out[1] = b * inv;
    }
}

extern "C" void kernel_launch(void* const* d_in, const int* in_sizes, int n_in,
                              void* d_out, int out_size, void* d_ws, size_t ws_size,
                              hipStream_t stream) {
    const float* zxs = (const float*)d_in[0];
    const float* zys = (const float*)d_in[1];
    const float* zxt = (const float*)d_in[2];
    const float* zyt = (const float*)d_in[3];

    char* ws = (char*)d_ws;
    const size_t A = (size_t)N * D;                   // bytes per fp8 array
    unsigned char* nb = (unsigned char*)ws;           // 4 normalized fp8 arrays (tiled)
    float* partial  = (float*)(ws + 4 * A);           // [32][N][4] f32 = 2 MB
    float* blocksum = (float*)(ws + 4 * A + (size_t)32 * N * 4 * sizeof(float));

    norm4<<<dim3(N / 32, 4), 256, 0, stream>>>(zxs, zys, zxt, zyt, nb);

    const unsigned char* Xs = nb;
    const unsigned char* Ys = nb + A;
    const unsigned char* Xt = nb + 2 * A;
    const unsigned char* Yt = nb + 3 * A;
    fused_gemm<<<dim3(1024), 256, 0, stream>>>(Xs, Ys, Xt, Yt, partial);

    reduce_rows<<<16, 256, 0, stream>>>(partial, blocksum);
    final_reduce<<<1, 64, 0, stream>>>(blocksum, (float*)d_out);
}

// Round 15
// 51.293 us; speedup vs baseline: 1.7505x; 1.0440x over previous
//
#include <hip/hip_runtime.h>
#include <hip/hip_bf16.h>

#define N 4096
#define D 768
#define NC 6    // D/128 K-chunks per gemm pass

typedef float f32x4 __attribute__((ext_vector_type(4)));
typedef int v8i __attribute__((ext_vector_type(8)));

typedef __attribute__((address_space(3))) unsigned int as3_uint;
typedef const __attribute__((address_space(1))) unsigned int as1_uint;

__device__ __forceinline__ void gload16(const void* g, void* l) {
    __builtin_amdgcn_global_load_lds((as1_uint*)g, (as3_uint*)l, 16, 0, 0);
}

// Tiled fp8 global layout for mfma_scale_f32_16x16x128_f8f6f4 (R7-verified):
// frag-tile = 16 rows x 128 k = 2048B, tile index (R>>4)*6 + (k>>7).
// Within a tile: lane l = (R&15) + 16*((k&127)>>5) holds 32 contiguous k,
// stored as two lane-linear 1024B halves (byte = half*1024 + l*16 + (k&15)).

// ---------------- normalize: f32 [N][D] -> fp8 tiled, row L2-normalized ------
// blockIdx.x -> rg remapped so the producing block's XCD (= linear bid % 8)
// matches the consumer set in fused_gemm's 2D XCD partition:
//   X arrays (a=0,2): band rg>>5 consumed by xcds {2*band, 2*band+1}
//   Y arrays (a=1,3): rg<64 consumed by even xcds, rg>=64 by odd xcds
__global__ __launch_bounds__(256) void norm4(const float* __restrict__ x0,
                                             const float* __restrict__ x1,
                                             const float* __restrict__ x2,
                                             const float* __restrict__ x3,
                                             unsigned char* __restrict__ o) {
    int a = blockIdx.y;
    const float* x = (a == 0) ? x0 : (a == 1) ? x1 : (a == 2) ? x2 : x3;
    unsigned char* out = o + (size_t)a * N * D;
    int xb = blockIdx.x;
    int rg;
    if (a & 1) {
        rg = (xb & 1) * 64 + (xb >> 1);                       // Y: parity -> jb half
    } else {
        int band = (xb & 7) >> 1;                             // X: xcd pair -> ib band
        rg = band * 32 + ((xb >> 3) << 1) + (xb & 1);
    }
    int i0 = rg * 32;                 // 32-row group
    __shared__ __align__(16) unsigned char tile[24576];
    int t = threadIdx.x, lane = t & 63, w = t >> 6;

    for (int rr = 0; rr < 8; ++rr) {
        int R = i0 + w * 8 + rr;
        const f32x4* xr = (const f32x4*)(x + (size_t)R * D);
        f32x4 v0 = xr[lane * 2], v1 = xr[lane * 2 + 1];
        f32x4 v2 = {}, v3 = {};
        if (lane < 32) { v2 = xr[128 + lane * 2]; v3 = xr[128 + lane * 2 + 1]; }
        float ss = v0[0]*v0[0] + v0[1]*v0[1] + v0[2]*v0[2] + v0[3]*v0[3]
                 + v1[0]*v1[0] + v1[1]*v1[1] + v1[2]*v1[2] + v1[3]*v1[3]
                 + v2[0]*v2[0] + v2[1]*v2[1] + v2[2]*v2[2] + v2[3]*v2[3]
                 + v3[0]*v3[0] + v3[1]*v3[1] + v3[2]*v3[2] + v3[3]*v3[3];
        #pragma unroll
        for (int m = 1; m < 64; m <<= 1) ss += __shfl_xor(ss, m);
        float s = 1.0f / fmaxf(sqrtf(ss), 1e-8f);

        int lrg = (R >> 4) & 1;
        {
            unsigned int wlo = __builtin_amdgcn_cvt_pk_fp8_f32(v0[0]*s, v0[1]*s, 0, false) & 0xffff;
            unsigned int whi = __builtin_amdgcn_cvt_pk_fp8_f32(v0[2]*s, v0[3]*s, 0, false) & 0xffff;
            unsigned int w0 = wlo | (whi << 16);
            wlo = __builtin_amdgcn_cvt_pk_fp8_f32(v1[0]*s, v1[1]*s, 0, false) & 0xffff;
            whi = __builtin_amdgcn_cvt_pk_fp8_f32(v1[2]*s, v1[3]*s, 0, false) & 0xffff;
            unsigned int w1 = wlo | (whi << 16);
            int g = lane;
            int off = (lrg * 6 + (g >> 4)) * 2048 + ((g >> 1) & 1) * 1024
                    + ((R & 15) + 16 * ((g & 15) >> 2)) * 16 + (g & 1) * 8;
            *(uint2*)(tile + off) = make_uint2(w0, w1);
        }
        if (lane < 32) {
            unsigned int wlo = __builtin_amdgcn_cvt_pk_fp8_f32(v2[0]*s, v2[1]*s, 0, false) & 0xffff;
            unsigned int whi = __builtin_amdgcn_cvt_pk_fp8_f32(v2[2]*s, v2[3]*s, 0, false) & 0xffff;
            unsigned int w0 = wlo | (whi << 16);
            wlo = __builtin_amdgcn_cvt_pk_fp8_f32(v3[0]*s, v3[1]*s, 0, false) & 0xffff;
            whi = __builtin_amdgcn_cvt_pk_fp8_f32(v3[2]*s, v3[3]*s, 0, false) & 0xffff;
            unsigned int w1 = wlo | (whi << 16);
            int g = 64 + lane;
            int off = (lrg * 6 + (g >> 4)) * 2048 + ((g >> 1) & 1) * 1024
                    + ((R & 15) + 16 * ((g & 15) >> 2)) * 16 + (g & 1) * 8;
            *(uint2*)(tile + off) = make_uint2(w0, w1);
        }
    }
    __syncthreads();
    unsigned char* dst = out + (size_t)rg * 24576;
    #pragma unroll
    for (int i = 0; i < 6; ++i)
        ((int4*)dst)[t + i * 256] = ((const int4*)tile)[t + i * 256];
}

// ---------------- one gemm pass: acc += A_blk(128) x B_blk(128)^T ------------
// R7/R12-verified structure + pass-boundary prefetch: at c==NC-1, if a next
// pass exists, ISSUE its chunk 0 (into buf0 — parity-continuous since NC is
// even) and keep the counted vmcnt(8); no mid-kernel drain.
__device__ __forceinline__ void gemm_pass(const unsigned char* __restrict__ A,
                                          const unsigned char* __restrict__ B,
                                          const unsigned char* __restrict__ An,
                                          const unsigned char* __restrict__ Bn,
                                          char* smem, int ib, int jb, int t,
                                          f32x4 (&acc)[4][4], bool first) {
    const int lane = t & 63, w = t >> 6;
    const int wm = w >> 1, wn = w & 1;

    const size_t offA = (size_t)((ib * 8 + 2 * w) * 6) * 2048 + lane * 16;
    const size_t offB = (size_t)((jb * 8 + 2 * w) * 6) * 2048 + lane * 16;
    const unsigned char* gA = A + offA;
    const unsigned char* gB = B + offB;
    const int sd = w * 4096 + lane * 16;

    #define ISSUE2(pA, pB, par, c)  do {                                       \
        char* buf = smem + (par) * 32768;                                      \
        const unsigned char* sa = (pA) + (c) * 2048;                           \
        const unsigned char* sb = (pB) + (c) * 2048;                           \
        gload16(sa,         buf + sd);                                         \
        gload16(sa + 1024,  buf + sd + 1024);                                  \
        gload16(sa + 12288, buf + sd + 2048);                                  \
        gload16(sa + 13312, buf + sd + 3072);                                  \
        gload16(sb,         buf + 16384 + sd);                                 \
        gload16(sb + 1024,  buf + 16384 + sd + 1024);                          \
        gload16(sb + 12288, buf + 16384 + sd + 2048);                          \
        gload16(sb + 13312, buf + 16384 + sd + 3072);                          \
    } while (0)

    if (first) ISSUE2(gA, gB, 0, 0);

    #pragma unroll 1
    for (int c = 0; c < NC; ++c) {
        if (c < NC - 1) {
            ISSUE2(gA, gB, (c + 1) & 1, c + 1);
            asm volatile("s_waitcnt vmcnt(8)" ::: "memory");  // c staged, c+1 in flight
        } else if (An != nullptr) {
            const unsigned char* gAn = An + offA;
            const unsigned char* gBn = Bn + offB;
            ISSUE2(gAn, gBn, 0, 0);                           // next pass chunk 0
            asm volatile("s_waitcnt vmcnt(8)" ::: "memory");  // c staged, next in flight
        } else {
            asm volatile("s_waitcnt vmcnt(0)" ::: "memory");  // final tail: drain
        }
        __builtin_amdgcn_s_barrier();
        asm volatile("" ::: "memory");

        const char* cb = smem + (c & 1) * 32768;
        union { int4 q[2]; v8i v; } a[4], b[4];
        #pragma unroll
        for (int m = 0; m < 4; ++m) {
            const char* p = cb + (wm * 4 + m) * 2048 + lane * 16;
            a[m].q[0] = *(const int4*)p;
            a[m].q[1] = *(const int4*)(p + 1024);
        }
        #pragma unroll
        for (int n = 0; n < 4; ++n) {
            const char* p = cb + 16384 + (wn * 4 + n) * 2048 + lane * 16;
            b[n].q[0] = *(const int4*)p;
            b[n].q[1] = *(const int4*)(p + 1024);
        }
        __builtin_amdgcn_s_setprio(1);
        #pragma unroll
        for (int m = 0; m < 4; ++m)
            #pragma unroll
            for (int n = 0; n < 4; ++n)
                acc[m][n] = __builtin_amdgcn_mfma_scale_f32_16x16x128_f8f6f4(
                    a[m].v, b[n].v, acc[m][n], 0, 0, 0, 127, 0, 127);
        __builtin_amdgcn_s_setprio(0);
        __builtin_amdgcn_s_barrier();   // all reads of buffer c done
    }
    #undef ISSUE2
}

__global__ __launch_bounds__(256, 2) void fused_gemm(
        const unsigned char* __restrict__ Xs, const unsigned char* __restrict__ Ys,
        const unsigned char* __restrict__ Xt, const unsigned char* __restrict__ Yt,
        float* __restrict__ partial) {
    __shared__ __align__(16) char smem[65536];
    const int t = threadIdx.x;
    // 2D XCD partition (R12-verified: FETCH 28->18.5 MB): xcd = bid&7.
    const int bid = blockIdx.x;
    const int xcd = bid & 7, loc = bid >> 3;          // loc 0..127
    const int ib = (xcd >> 1) * 8 + (loc & 7);
    const int jb = (xcd & 1) * 16 + (loc >> 3);
    const int i0 = ib * 128;
    const int lane = t & 63, wid = t >> 6;
    const int wm = wid >> 1, wn = wid & 1;

    f32x4 acc_s[4][4] = {};
    f32x4 acc_t[4][4] = {};

    gemm_pass(Xs, Ys, Xt, Yt, smem, ib, jb, t, acc_s, true);
    gemm_pass(Xt, Yt, nullptr, nullptr, smem, ib, jb, t, acc_t, false);

    // ---- epilogue v2 (R14-verified): scatter-transpose via LDS --------------
    __syncthreads();
    float* p2 = (float*)smem;
    const int g = lane >> 4, cl = lane & 15;
    const int slot = wn * 16 + cl;

    #pragma unroll
    for (int m = 0; m < 4; ++m)
        #pragma unroll
        for (int r = 0; r < 4; ++r) {
            float e0 = 0.f, e1 = 0.f, e2 = 0.f, e3 = 0.f;
            #pragma unroll
            for (int n = 0; n < 4; ++n) {
                float ls = 10.0f * acc_s[m][n][r];
                float lt = 10.0f * acc_t[m][n][r];
                float es = __expf(ls - 10.0f);
                float et = __expf(lt - 10.0f);
                e0 += es;
                e1 += et;
                e2 += es * (ls - lt);
                e3 += et * (lt - ls);
            }
            int row = wm * 64 + m * 16 + g * 4 + r;   // 0..127
            int cell = row ^ (cl & 7);
            f32x4 vv = {e0, e1, e2, e3};
            *(f32x4*)(p2 + slot * 512 + cell * 4) = vv;
        }
    __syncthreads();

    {
        const int row = t >> 1, half = t & 1;
        f32x4 sum = {0.f, 0.f, 0.f, 0.f};
        #pragma unroll
        for (int j = 0; j < 16; ++j) {
            int sl = half * 16 + j;
            int cell = row ^ (sl & 7);
            sum += *(const f32x4*)(p2 + sl * 512 + cell * 4);
        }
        __syncthreads();                  // all reads of p2 done
        *(f32x4*)(p2 + t * 4) = sum;      // p3[256][4]
    }
    __syncthreads();
    #pragma unroll
    for (int q = 0; q < 2; ++q) {
        int idx2 = t + q * 256;           // 512 slots = 128 rows x 4 stats
        int row = idx2 >> 2, s = idx2 & 3;
        float v = p2[(row * 2) * 4 + s] + p2[(row * 2 + 1) * 4 + s];
        partial[((size_t)jb * N + (i0 + row)) * 4 + s] = v;
    }
}

// ---------------- per-row finalize + block partial sums ----------------------
__global__ __launch_bounds__(256) void reduce_rows(const float* __restrict__ partial,
                                                   float* __restrict__ blocksum) {
    int row = blockIdx.x * 256 + threadIdx.x;
    float zs = 0.f, zt = 0.f, ws = 0.f, wt = 0.f;
    for (int jb = 0; jb < 32; ++jb) {
        const float* p = partial + ((size_t)jb * N + row) * 4;
        zs += p[0]; zt += p[1]; ws += p[2]; wt += p[3];
    }
    float ls_row = wt / zt - logf(zt) + logf(zs);
    float lt_row = ws / zs - logf(zs) + logf(zt);
    #pragma unroll
    for (int m = 1; m < 64; m <<= 1) {
        ls_row += __shfl_xor(ls_row, m);
        lt_row += __shfl_xor(lt_row, m);
    }
    __shared__ float rs[4], rt[4];
    int lane = threadIdx.x & 63, wid = threadIdx.x >> 6;
    if (lane == 0) { rs[wid] = ls_row; rt[wid] = lt_row; }
    __syncthreads();
    if (threadIdx.x == 0) {
        blocksum[blockIdx.x * 2]     = rs[0] + rs[1] + rs[2] + rs[3];
        blocksum[blockIdx.x * 2 + 1] = rt[0] + rt[1] + rt[2] + rt[3];
    }
}

__global__ void final_reduce(const float* __restrict__ blocksum, float* __restrict__ out) {
    float a = 0.f, b = 0.f;
    if (threadIdx.x < 16) { a = blocksum[threadIdx.x * 2]; b = blocksum[threadIdx.x * 2 + 1]; }
    #pragma unroll
    for (int m = 1; m < 16; m <<= 1) { a += __shfl_xor(a, m); b += __shfl_xor(b, m); }
    if (threadIdx.x == 0) {
        const float inv = 1.0f / 16777216.0f;   // 1/N^2
        out[0] = a * inv;
        out[1] = b * inv;
    }
}

extern "C" void kernel_launch(void* const* d_in, const int* in_sizes, int n_in,
                              void* d_out, int out_size, void* d_ws, size_t ws_size,
                              hipStream_t stream) {
    const float* zxs = (const float*)d_in[0];
    const float* zys = (const float*)d_in[1];
    const float* zxt = (const float*)d_in[2];
    const float* zyt = (const float*)d_in[3];

    char* ws = (char*)d_ws;
    const size_t A = (size_t)N * D;                   // bytes per fp8 array
    unsigned char* nb = (unsigned char*)ws;           // 4 normalized fp8 arrays (tiled)
    float* partial  = (float*)(ws + 4 * A);           // [32][N][4] f32 = 2 MB
    float* blocksum = (float*)(ws + 4 * A + (size_t)32 * N * 4 * sizeof(float));

    norm4<<<dim3(N / 32, 4), 256, 0, stream>>>(zxs, zys, zxt, zyt, nb);

    const unsigned char* Xs = nb;
    const unsigned char* Ys = nb + A;
    const unsigned char* Xt = nb + 2 * A;
    const unsigned char* Yt = nb + 3 * A;
    fused_gemm<<<dim3(1024), 256, 0, stream>>>(Xs, Ys, Xt, Yt, partial);

    reduce_rows<<<16, 256, 0, stream>>>(partial, blocksum);
    final_reduce<<<1, 64, 0, stream>>>(blocksum, (float*)d_out);
}